// Round 1
// 582.163 us; speedup vs baseline: 1.0839x; 1.0839x over previous
//
#include <hip/hip_runtime.h>

#define B_ 2048
#define T_ 256
#define F_ 128
#define H_ 64

typedef __attribute__((ext_vector_type(8))) short short8;   // 8 bf16
typedef __attribute__((ext_vector_type(4))) float f32x4;

// pack two floats to adjacent bf16 (RNE): low16 = a, high16 = b
__device__ __forceinline__ unsigned int rne2(float fa, float fb) {
    unsigned int ua = __float_as_uint(fa);
    unsigned int ub = __float_as_uint(fb);
    ua = ua + 0x7fffu + ((ua >> 16) & 1u);
    ub = ub + 0x7fffu + ((ub >> 16) & 1u);
    return (ua >> 16) | (ub & 0xffff0000u);
}
__device__ __forceinline__ float sigmoid_f(float v) {
    return __fdividef(1.0f, 1.0f + __expf(-v));
}
__device__ __forceinline__ float tanh_f(float v) {
    return 1.0f - __fdividef(2.0f, 1.0f + __expf(2.0f * v));  // overflow -> +/-1 correct
}

// 256 threads = 4 waves. Block owns 4 batch rows for all T=256 steps.
// Wave wv owns hidden dims [16*wv, 16*wv+16)  (N-tiles g*4 + wv, g in {r,z,n}).
// -> grid 512 blocks x 4 waves = 2048 waves = 2 independent waves/SIMD.
// gx M-tile packs 2 timesteps x 4 rows x 2 replication: m = (sl<<3)|(rep<<2)|row.
// C-layout (verified r3): row_slot = (j>>4)*4+reg, col = tile*16 + (j&15).
// w_hh B-frags are loop-invariant per wave (6 x short8 = 24 VGPR) -> registers,
// gathered directly from global; whhf LDS buffer removed entirely.
// h kept in LDS as pre-split bf16 hi/lo (double-buffered), 1 barrier/step.
__global__ __launch_bounds__(256, 2) void gru_fused(
    const float* __restrict__ x, const float* __restrict__ w_ih,
    const float* __restrict__ w_hh, const float* __restrict__ b_ih,
    const float* __restrict__ b_hh, const float* __restrict__ fc_w,
    const float* __restrict__ fc_b, float* __restrict__ out)
{
    __shared__ __align__(16) short wihf[12 * 4 * 64 * 8];   // 48 KB B-frags (bf16)
    __shared__ __align__(16) short hhi_l[2][4][72];         // h hi bf16, dbuf, pad 72
    __shared__ __align__(16) short hlo_l[2][4][72];         // h lo bf16
    __shared__ float wred[4][4];

    const int tid = threadIdx.x;
    const int wv  = tid >> 6;          // 0..3
    const int j   = tid & 63;
    const int q   = j >> 4;            // 0..3
    const int c   = j & 15;            // 0..15
    const int brow = blockIdx.x * 4;

    // ---- stage w_ih B-frags: slot s=(tile*4+ks)*64+L  el e = w_ih[tile*16+(L&15)][ks*32+(L>>4)*8+e]
    for (int s = tid; s < 12 * 4 * 64; s += 256) {
        const int n = s >> 8, ks = (s >> 6) & 3, L = s & 63;
        const float* wp = w_ih + (n * 16 + (L & 15)) * F_ + ks * 32 + ((L >> 4) * 8);
        const float4 a = *(const float4*)wp;
        const float4 b = *(const float4*)(wp + 4);
        union { short8 v; unsigned int u[4]; } fr;
        fr.u[0] = rne2(a.x, a.y); fr.u[1] = rne2(a.z, a.w);
        fr.u[2] = rne2(b.x, b.y); fr.u[3] = rne2(b.z, b.w);
        *(short8*)&wihf[s * 8] = fr.v;
    }
    // ---- zero h buffers
    for (int i = tid; i < 2 * 4 * 72; i += 256) {
        ((short*)hhi_l)[i] = 0;
        ((short*)hlo_l)[i] = 0;
    }

    // ---- per-lane constants (wave owns 16 dims; one dim per lane-column)
    const int d0 = wv * 16 + c;
    const float bxr = b_ih[d0],       bgr = b_hh[d0];
    const float bxz = b_ih[64 + d0],  bgz = b_hh[64 + d0];
    const float bxn = b_ih[128 + d0], bgn = b_hh[128 + d0];
    const float fw0 = fc_w[d0];

    // ---- w_hh B-frags -> registers (loop-invariant): wh[g][ks2]
    // el e = w_hh[(g*4+wv)*16 + c][ks2*32 + q*8 + e]
    short8 wh[3][2];
    #pragma unroll
    for (int g = 0; g < 3; ++g) {
        #pragma unroll
        for (int ks2 = 0; ks2 < 2; ++ks2) {
            const float* wp = w_hh + (g * 64 + wv * 16 + c) * H_ + ks2 * 32 + q * 8;
            const float4 a = *(const float4*)wp;
            const float4 b = *(const float4*)(wp + 4);
            union { short8 v; unsigned int u[4]; } fr;
            fr.u[0] = rne2(a.x, a.y); fr.u[1] = rne2(a.z, a.w);
            fr.u[2] = rne2(b.x, b.y); fr.u[3] = rne2(b.z, b.w);
            wh[g][ks2] = fr.v;
        }
    }

    // A-side x mapping: m = j&15 -> sl = m>>3 (step in pack), row = m&3 (rep bit m&4)
    const int xrow = (j & 15) & 3;
    const int xsl  = (j & 15) >> 3;
    const float* xlane = x + ((size_t)(brow + xrow) * T_ + xsl) * F_ + q * 8;

    __syncthreads();   // frags + zeroed h visible

    // ---- x register prefetch: 2 macro-steps deep
    float4 XA[8], XB[8];
    {
        const float* lp = xlane;
        #pragma unroll
        for (int ks = 0; ks < 4; ++ks) {
            XA[2 * ks]     = *(const float4*)(lp + ks * 32);
            XA[2 * ks + 1] = *(const float4*)(lp + ks * 32 + 4);
        }
        lp = xlane + 2 * F_;
        #pragma unroll
        for (int ks = 0; ks < 4; ++ks) {
            XB[2 * ks]     = *(const float4*)(lp + ks * 32);
            XB[2 * ks + 1] = *(const float4*)(lp + ks * 32 + 4);
        }
    }

    short8 af[4], hh[2], hl[2];
    const short8 z8 = {0, 0, 0, 0, 0, 0, 0, 0};
    hh[0] = z8; hh[1] = z8; hl[0] = z8; hl[1] = z8;

    auto cvtbuf = [&](float4 (&Xv)[8]) {
        #pragma unroll
        for (int ks = 0; ks < 4; ++ks) {
            union { short8 v; unsigned int u[4]; } fr;
            fr.u[0] = rne2(Xv[2 * ks].x,     Xv[2 * ks].y);
            fr.u[1] = rne2(Xv[2 * ks].z,     Xv[2 * ks].w);
            fr.u[2] = rne2(Xv[2 * ks + 1].x, Xv[2 * ks + 1].y);
            fr.u[3] = rne2(Xv[2 * ks + 1].z, Xv[2 * ks + 1].w);
            af[ks] = fr.v;
        }
    };
    cvtbuf(XA);   // frags for t0=0

    auto do_macro = [&](float4 (&Xre)[8], float4 (&Xcv)[8], int t0) {
        // ===== gx for 2 packed steps (x single-bf16), one N-tile per gate =====
        f32x4 axr = {bxr, bxr, bxr, bxr};
        f32x4 axz = {bxz, bxz, bxz, bxz};
        f32x4 axn = {bxn, bxn, bxn, bxn};
        {
            const int tr = (0 + wv) * 2048;   // short-index tile bases
            const int tz = (4 + wv) * 2048;
            const int tn = (8 + wv) * 2048;
            #pragma unroll
            for (int ks = 0; ks < 4; ++ks) {
                axr = __builtin_amdgcn_mfma_f32_16x16x32_bf16(
                    af[ks], *(const short8*)&wihf[tr + ks * 512 + j * 8], axr, 0, 0, 0);
                axz = __builtin_amdgcn_mfma_f32_16x16x32_bf16(
                    af[ks], *(const short8*)&wihf[tz + ks * 512 + j * 8], axz, 0, 0, 0);
                axn = __builtin_amdgcn_mfma_f32_16x16x32_bf16(
                    af[ks], *(const short8*)&wihf[tn + ks * 512 + j * 8], axn, 0, 0, 0);
            }
        }
        // ===== prefetch x for t0+4 =====
        {
            int tl = t0 + 4; if (tl > 254) tl = 254;
            const float* lp = xlane + (size_t)tl * F_;
            #pragma unroll
            for (int ks = 0; ks < 4; ++ks) {
                Xre[2 * ks]     = *(const float4*)(lp + ks * 32);
                Xre[2 * ks + 1] = *(const float4*)(lp + ks * 32 + 4);
            }
        }
        // ===== two recurrence steps =====
        auto step = [&](int s) {
            f32x4 agr = {bgr, bgr, bgr, bgr};
            f32x4 agz = {bgz, bgz, bgz, bgz};
            f32x4 agn = {bgn, bgn, bgn, bgn};
            #pragma unroll
            for (int ks2 = 0; ks2 < 2; ++ks2) {
                agr = __builtin_amdgcn_mfma_f32_16x16x32_bf16(hh[ks2], wh[0][ks2], agr, 0, 0, 0);
                agr = __builtin_amdgcn_mfma_f32_16x16x32_bf16(hl[ks2], wh[0][ks2], agr, 0, 0, 0);
                agz = __builtin_amdgcn_mfma_f32_16x16x32_bf16(hh[ks2], wh[1][ks2], agz, 0, 0, 0);
                agz = __builtin_amdgcn_mfma_f32_16x16x32_bf16(hl[ks2], wh[1][ks2], agz, 0, 0, 0);
                agn = __builtin_amdgcn_mfma_f32_16x16x32_bf16(hh[ks2], wh[2][ks2], agn, 0, 0, 0);
                agn = __builtin_amdgcn_mfma_f32_16x16x32_bf16(hl[ks2], wh[2][ks2], agn, 0, 0, 0);
            }
            // gates: active lanes q>>1 == s hold this step's gx rows (C rows 8s..8s+7)
            if ((q >> 1) == s) {
                const int rowsel = q & 1;     // dedupe the m&4 replication
                #pragma unroll
                for (int rl = 0; rl < 2; ++rl) {
                    const int row = rowsel * 2 + rl;
                    const int e   = rowsel * 2 + rl;
                    const float vr  = axr[e] + agr[e];
                    const float vz  = axz[e] + agz[e];
                    const float r = sigmoid_f(vr);
                    const float z = sigmoid_f(vz);
                    const float n = tanh_f(axn[e] + r * agn[e]);
                    const float hp =
                        __uint_as_float(((unsigned int)(unsigned short)hhi_l[s][row][d0]) << 16) +
                        __uint_as_float(((unsigned int)(unsigned short)hlo_l[s][row][d0]) << 16);
                    const float hn = n + z * (hp - n);
                    const unsigned int uh = __float_as_uint(hn);
                    const unsigned int rr = uh + 0x7fffu + ((uh >> 16) & 1u);
                    const float hif = __uint_as_float(rr & 0xffff0000u);
                    const float lof = hn - hif;
                    const unsigned int ul = __float_as_uint(lof);
                    const unsigned int r2 = ul + 0x7fffu + ((ul >> 16) & 1u);
                    hhi_l[s ^ 1][row][d0] = (short)(rr >> 16);
                    hlo_l[s ^ 1][row][d0] = (short)(r2 >> 16);
                }
            }
            __syncthreads();
            // reload h A-frags for next step (zero-convert: pre-split bf16 in LDS)
            #pragma unroll
            for (int ks2 = 0; ks2 < 2; ++ks2) {
                hh[ks2] = *(const short8*)&hhi_l[s ^ 1][xrow][ks2 * 32 + q * 8];
                hl[ks2] = *(const short8*)&hlo_l[s ^ 1][xrow][ks2 * 32 + q * 8];
            }
        };
        step(0);
        step(1);
        // ===== convert next macro's x =====
        cvtbuf(Xcv);
    };

    #pragma unroll 1
    for (int t0 = 0; t0 < T_; t0 += 4) {
        do_macro(XA, XB, t0);
        do_macro(XB, XA, t0 + 2);
    }

    // ===== epilogue: out[brow+r] = h[r] . fc_w + fc_b  (final h in buffer 0) =====
    {
        const int row = q;
        const float hv0 =
            __uint_as_float(((unsigned int)(unsigned short)hhi_l[0][row][d0]) << 16) +
            __uint_as_float(((unsigned int)(unsigned short)hlo_l[0][row][d0]) << 16);
        float partial = hv0 * fw0;
        #pragma unroll
        for (int m = 1; m <= 8; m <<= 1) partial += __shfl_xor(partial, m, 64);
        if (c == 0) wred[wv][q] = partial;
        __syncthreads();
        if (tid < 4)
            out[brow + tid] = wred[0][tid] + wred[1][tid] + wred[2][tid] + wred[3][tid] + fc_b[0];
    }
}

extern "C" void kernel_launch(void* const* d_in, const int* in_sizes, int n_in,
                              void* d_out, int out_size, void* d_ws, size_t ws_size,
                              hipStream_t stream)
{
    (void)in_sizes; (void)n_in; (void)out_size; (void)d_ws; (void)ws_size;
    const float* x    = (const float*)d_in[0];
    const float* w_ih = (const float*)d_in[1];
    const float* w_hh = (const float*)d_in[2];
    const float* b_ih = (const float*)d_in[3];
    const float* b_hh = (const float*)d_in[4];
    const float* fc_w = (const float*)d_in[5];
    const float* fc_b = (const float*)d_in[6];
    float* out = (float*)d_out;

    gru_fused<<<dim3(B_ / 4), 256, 0, stream>>>(
        x, w_ih, w_hh, b_ih, b_hh, fc_w, fc_b, out);
}